// Round 3
// baseline (138.414 us; speedup 1.0000x reference)
//
#include <hip/hip_runtime.h>
#include <math.h>

#define VOCAB  50000
#define D_EMB  300
#define NBINS  11
#define BATCH  64
#define LQ     32
#define LD     1024
#define DTILE  64
#define NDT    (LD / DTILE)   // 16
#define NSTEP  10             // K padded to 320 = 10 * 32 (MFMA K=32 steps)
#define FRAG_BLOCK (NSTEP * 512)   // shorts per 16-row fragment region

typedef __attribute__((ext_vector_type(8))) short short8;   // 8 bf16 (4 VGPRs)
typedef __attribute__((ext_vector_type(4))) float floatx4;  // MFMA C/D

__constant__ float c_mu[NBINS]  = {1.0f, 0.9f, 0.7f, 0.5f, 0.3f, 0.1f,
                                   -0.1f, -0.3f, -0.5f, -0.7f, -0.9f};
// 1 / (2*sigma^2): sigma=1e-3 -> 5e5 ; sigma=0.1 -> 50
__constant__ float c_is2[NBINS] = {500000.0f, 50.f, 50.f, 50.f, 50.f, 50.f,
                                   50.f, 50.f, 50.f, 50.f, 50.f};

static __device__ __forceinline__ unsigned short f32_bf16(float f) {
  unsigned u = __float_as_uint(f);
  u += 0x7FFFu + ((u >> 16) & 1u);          // RNE
  return (unsigned short)(u >> 16);
}
static __device__ __forceinline__ float bf16_f32(unsigned short h) {
  return __uint_as_float(((unsigned)h) << 16);
}

// Stage one 16-row region into MFMA-fragment-linear layout (LDS or global).
// Lane l holds row (l&15), k-chunk 8*(l>>4) of each 32-wide k-step. Writes are
// *_b128 at base + l*16 -> conflict-free / fully coalesced. Returns this
// lane's sum-of-squares partial over the bf16-ROUNDED values it staged.
// NOTE: the p-accumulation order here + shfl_xor(16),shfl_xor(32) must stay
// identical between prep (q rows) and main (d rows) so an exact token match
// produces bitwise-identical norms -> sim == 1 -> bin-0 (sigma=1e-3) exact.
static __device__ __forceinline__ float stage_rows(
    const float* __restrict__ emb_row,   // word_emb + tok*D_EMB (this lane's row)
    short* __restrict__ region,          // fragment region base
    int khi, int lane)
{
  const float4* emb4 = (const float4*)emb_row;
  float p = 0.f;
#pragma unroll
  for (int s = 0; s < NSTEP; ++s) {
    const int k0 = 32 * s + 8 * khi;
    float4 fa = make_float4(0.f, 0.f, 0.f, 0.f);
    float4 fb = make_float4(0.f, 0.f, 0.f, 0.f);
    if (k0 < D_EMB)     fa = emb4[k0 >> 2];        // k0 mult of 8 -> full float4 ok
    if (k0 + 4 < D_EMB) fb = emb4[(k0 >> 2) + 1];  // zero-pad K 300..319
    unsigned short h[8];
    h[0] = f32_bf16(fa.x); h[1] = f32_bf16(fa.y);
    h[2] = f32_bf16(fa.z); h[3] = f32_bf16(fa.w);
    h[4] = f32_bf16(fb.x); h[5] = f32_bf16(fb.y);
    h[6] = f32_bf16(fb.z); h[7] = f32_bf16(fb.w);
    short8 v;
#pragma unroll
    for (int j = 0; j < 8; ++j) {
      const float x = bf16_f32(h[j]);   // norm from ROUNDED values
      p += x * x;
      v[j] = (short)h[j];
    }
    *(short8*)(region + s * 512 + lane * 8) = v;
  }
  return p;
}

// Prep: build bf16 A fragments + invq for all (b, q) rows ONCE (was re-staged
// 16x per batch by the main grid). 64 blocks x 2 waves; wave w = q-tile w.
__global__ __launch_bounds__(128) void knrm_prep(
    const int* __restrict__ inputs_q, const float* __restrict__ word_emb,
    short* __restrict__ afrag, float* __restrict__ invq)
{
  const int b    = blockIdx.x;
  const int qt   = threadIdx.x >> 6;
  const int lane = threadIdx.x & 63;
  const int khi  = lane >> 4, rl = lane & 15;
  const int tok  = inputs_q[b * LQ + 16 * qt + rl];
  float p = stage_rows(word_emb + (size_t)tok * D_EMB,
                       afrag + (size_t)(b * 2 + qt) * FRAG_BLOCK, khi, lane);
  p += __shfl_xor(p, 16); p += __shfl_xor(p, 32);
  if (lane < 16) invq[b * LQ + 16 * qt + lane] = 1.f / fmaxf(sqrtf(p), 1e-12f);
}

// Main: one block = (batch b, d-tile of 64 doc tokens). A fragments come from
// global (registers), B staged to LDS, bf16 MFMA, RBF + pooling epilogue.
__global__ __launch_bounds__(256) void knrm_main(
    const int* __restrict__ inputs_d, const float* __restrict__ mask_d,
    const float* __restrict__ word_emb, const short* __restrict__ afrag,
    const float* __restrict__ invq, float* __restrict__ partial)
{
  const int b    = blockIdx.y;
  const int dt   = blockIdx.x;
  const int tid  = threadIdx.x;
  const int wid  = tid >> 6;
  const int lane = tid & 63;
  const int khi  = lane >> 4;   // 0..3
  const int rl   = lane & 15;   // 0..15
  const int qt   = wid >> 1;    // this wave's q-tile (0..1)
  const int dp   = wid & 1;     // this wave's d-pair  (0..1)

  __shared__ __align__(16) short Bfrag[4 * FRAG_BLOCK];   // 40 KB
  __shared__ float invd_raw[DTILE];
  __shared__ float maskd_s[DTILE];
  __shared__ float red[4][16][NBINS];

  // ---- A fragments + invq straight into registers (coalesced, L2-hot:
  //      each 10KB block is reused by 32 waves across the 16 dt blocks)
  short8 areg[NSTEP];
  {
    const short8* ag = (const short8*)(afrag + (size_t)(b * 2 + qt) * FRAG_BLOCK);
#pragma unroll
    for (int s = 0; s < NSTEP; ++s) areg[s] = ag[s * 64 + lane];
  }
  const float4 iq4 = *(const float4*)&invq[b * LQ + 16 * qt + 4 * khi];

  if (tid < DTILE) maskd_s[tid] = mask_d[b * LD + dt * DTILE + tid];

  // ---- B staging: wave w stages d-rows 16w..16w+15 (all 10 k-steps)
  {
    const int tok = inputs_d[b * LD + dt * DTILE + 16 * wid + rl];
    float p = stage_rows(word_emb + (size_t)tok * D_EMB,
                         Bfrag + wid * FRAG_BLOCK, khi, lane);
    p += __shfl_xor(p, 16); p += __shfl_xor(p, 32);
    if (lane < 16) invd_raw[16 * wid + lane] = p;   // raw sumsq
  }
  __syncthreads();

  // ---- MFMA: wave w computes C tiles qt x {2dp, 2dp+1}
  const short* B0 = Bfrag + (2 * dp) * FRAG_BLOCK;
  const short* B1 = B0 + FRAG_BLOCK;
  floatx4 acc0 = {0.f, 0.f, 0.f, 0.f};
  floatx4 acc1 = {0.f, 0.f, 0.f, 0.f};
#pragma unroll
  for (int s = 0; s < NSTEP; ++s) {
    const short8 b0 = *(const short8*)(B0 + s * 512 + lane * 8);
    const short8 b1 = *(const short8*)(B1 + s * 512 + lane * 8);
    acc0 = __builtin_amdgcn_mfma_f32_16x16x32_bf16(areg[s], b0, acc0, 0, 0, 0);
    acc1 = __builtin_amdgcn_mfma_f32_16x16x32_bf16(areg[s], b1, acc1, 0, 0, 0);
  }

  // ---- epilogue: normalize, RBF bins, pool over this wave's 32 d-cols
  float ps[4][NBINS];
#pragma unroll
  for (int r = 0; r < 4; ++r)
#pragma unroll
    for (int k = 0; k < NBINS; ++k) ps[r][k] = 0.f;

#pragma unroll
  for (int t = 0; t < 2; ++t) {
    const int   dl = 32 * dp + 16 * t + rl;               // C/D col = lane&15
    const float id = 1.f / fmaxf(sqrtf(invd_raw[dl]), 1e-12f);
    const float md = maskd_s[dl];
    const floatx4 acc = t ? acc1 : acc0;
#pragma unroll
    for (int r = 0; r < 4; ++r) {                         // C/D row = 4*khi+r
      const float sv = acc[r] * iq4[r] * id;
#pragma unroll
      for (int k = 0; k < NBINS; ++k) {
        const float d = sv - c_mu[k];
        ps[r][k] += md * __expf(-d * d * c_is2[k]);
      }
    }
  }

#pragma unroll
  for (int off = 1; off < 16; off <<= 1)
#pragma unroll
    for (int r = 0; r < 4; ++r)
#pragma unroll
      for (int k = 0; k < NBINS; ++k)
        ps[r][k] += __shfl_xor(ps[r][k], off);

  if (rl == 0)
#pragma unroll
    for (int r = 0; r < 4; ++r)
#pragma unroll
      for (int k = 0; k < NBINS; ++k)
        red[wid][4 * khi + r][k] = ps[r][k];
  __syncthreads();

  // partial layout: [b][q][k][dt] so finalize reads 16 contiguous floats
  for (int v = tid; v < LQ * NBINS; v += 256) {
    const int q = v / NBINS, k = v % NBINS;
    const float sv = (q < 16) ? (red[0][q][k] + red[1][q][k])
                              : (red[2][q - 16][k] + red[3][q - 16][k]);
    partial[((size_t)(b * LQ + q) * NBINS + k) * NDT + dt] = sv;
  }
}

// Finalize: reduce d-tiles, log, IDF attention weight, sum over q, dense+tanh.
__global__ __launch_bounds__(128) void knrm_finalize(
    const float* __restrict__ partial, const int* __restrict__ inputs_q,
    const float* __restrict__ mask_q, const float* __restrict__ attn_table,
    const float* __restrict__ idf_w, const float* __restrict__ idf_b,
    const float* __restrict__ dense_w, const float* __restrict__ dense_b,
    float* __restrict__ out)
{
  const int b   = blockIdx.x;
  const int tid = threadIdx.x;
  __shared__ float pool[LQ][NBINS];
  __shared__ float wq_s[LQ];
  __shared__ float lps[NBINS];

  for (int v = tid; v < LQ * NBINS; v += 128) {
    const int q = v / NBINS, k = v % NBINS;
    const float* p = partial + ((size_t)(b * LQ + q) * NBINS + k) * NDT;
    float s = 0.f;
#pragma unroll
    for (int t = 0; t < NDT; ++t) s += p[t];
    pool[q][k] = logf(fmaxf(s, 1e-10f));
  }
  if (tid < LQ) {
    const int tok = inputs_q[b * LQ + tid];
    wq_s[tid] = mask_q[b * LQ + tid] * (attn_table[tok] * idf_w[0] + idf_b[0]);
  }
  __syncthreads();
  if (tid < NBINS) {
    float s = 0.f;
    for (int q = 0; q < LQ; ++q) s += pool[q][tid] * wq_s[q];
    lps[tid] = 0.01f * s;
  }
  __syncthreads();
  if (tid == 0) {
    float z = dense_b[0];
    for (int k = 0; k < NBINS; ++k) z += lps[k] * dense_w[k];
    out[b] = tanhf(z);
  }
}

extern "C" void kernel_launch(void* const* d_in, const int* in_sizes, int n_in,
                              void* d_out, int out_size, void* d_ws, size_t ws_size,
                              hipStream_t stream) {
  const int*   inputs_q  = (const int*)d_in[0];
  const int*   inputs_d  = (const int*)d_in[1];
  const float* mask_q    = (const float*)d_in[2];
  const float* mask_d    = (const float*)d_in[3];
  const float* word_emb  = (const float*)d_in[4];
  const float* attn_tab  = (const float*)d_in[5];
  const float* idf_w     = (const float*)d_in[6];
  const float* idf_b     = (const float*)d_in[7];
  const float* dense_w   = (const float*)d_in[8];
  const float* dense_b   = (const float*)d_in[9];
  float* out = (float*)d_out;

  // ws layout: partial | afrag | invq   (ws is 256 MiB; we use < 6 MB)
  char*  ws      = (char*)d_ws;
  float* partial = (float*)ws;                         // 64*32*11*16 f32 = 1.44 MB
  short* afrag   = (short*)(ws + (2u << 20));          // 64*2*5120 bf16 = 1.31 MB
  float* invq    = (float*)(ws + (4u << 20));          // 2048 f32

  knrm_prep<<<BATCH, 128, 0, stream>>>(inputs_q, word_emb, afrag, invq);
  dim3 grid(NDT, BATCH);
  knrm_main<<<grid, 256, 0, stream>>>(inputs_d, mask_d, word_emb, afrag, invq, partial);
  knrm_finalize<<<BATCH, 128, 0, stream>>>(partial, inputs_q, mask_q, attn_tab,
                                           idf_w, idf_b, dense_w, dense_b, out);
}

// Round 4
// 138.000 us; speedup vs baseline: 1.0030x; 1.0030x over previous
//
#include <hip/hip_runtime.h>
#include <math.h>

#define VOCAB  50000
#define D_EMB  300
#define NBINS  11
#define BATCH  64
#define LQ     32
#define LD     1024
#define DTILE  64
#define NDT    (LD / DTILE)   // 16
#define NSTEP  10             // K padded to 320 = 10 * 32 (MFMA K=32 steps)
#define KPAD   320

typedef __attribute__((ext_vector_type(8))) short short8;   // 8 bf16 (4 VGPRs)
typedef __attribute__((ext_vector_type(4))) float floatx4;  // MFMA C/D

__constant__ float c_mu[NBINS]  = {1.0f, 0.9f, 0.7f, 0.5f, 0.3f, 0.1f,
                                   -0.1f, -0.3f, -0.5f, -0.7f, -0.9f};
// 1 / (2*sigma^2): sigma=1e-3 -> 5e5 ; sigma=0.1 -> 50
__constant__ float c_is2[NBINS] = {500000.0f, 50.f, 50.f, 50.f, 50.f, 50.f,
                                   50.f, 50.f, 50.f, 50.f, 50.f};

static __device__ __forceinline__ unsigned short f32_bf16(float f) {
  unsigned u = __float_as_uint(f);
  u += 0x7FFFu + ((u >> 16) & 1u);          // RNE
  return (unsigned short)(u >> 16);
}
static __device__ __forceinline__ float bf16_f32(unsigned short h) {
  return __uint_as_float(((unsigned)h) << 16);
}

// Vocab pass: canonical bf16 table (rows padded to 320, 640 B = 64 B-aligned)
// + invnorm computed FROM THE ROUNDED VALUES in one canonical order, so q and
// d lookups of the same token are bitwise identical -> bin-0 exactness.
// 3125 blocks x 256 thr; 16 rows/block, 16 threads/row, 40 short8 chunks/row.
__global__ __launch_bounds__(256) void knrm_vocab(
    const float* __restrict__ word_emb, short* __restrict__ emb_bf16,
    float* __restrict__ invnorm)
{
  const int row = blockIdx.x * 16 + (threadIdx.x >> 4);
  const int j   = threadIdx.x & 15;
  const float4* src = (const float4*)(word_emb + (size_t)row * D_EMB);
  short* dst = emb_bf16 + (size_t)row * KPAD;
  float p = 0.f;
#pragma unroll
  for (int cc = 0; cc < 3; ++cc) {
    const int c = j + 16 * cc;          // chunk id 0..39 (covers k=8c..8c+8)
    if (c < 40) {
      float4 fa = make_float4(0.f, 0.f, 0.f, 0.f);
      float4 fb = make_float4(0.f, 0.f, 0.f, 0.f);
      if (8 * c < D_EMB)     fa = src[2 * c];      // floats 8c..8c+3
      if (8 * c + 4 < D_EMB) fb = src[2 * c + 1];  // floats 8c+4..8c+7
      unsigned short h[8];
      h[0] = f32_bf16(fa.x); h[1] = f32_bf16(fa.y);
      h[2] = f32_bf16(fa.z); h[3] = f32_bf16(fa.w);
      h[4] = f32_bf16(fb.x); h[5] = f32_bf16(fb.y);
      h[6] = f32_bf16(fb.z); h[7] = f32_bf16(fb.w);
      short8 v;
#pragma unroll
      for (int t = 0; t < 8; ++t) {
        const float x = bf16_f32(h[t]);
        p += x * x;
        v[t] = (short)h[t];
      }
      *(short8*)(dst + 8 * c) = v;
    }
  }
  p += __shfl_xor(p, 1); p += __shfl_xor(p, 2);
  p += __shfl_xor(p, 4); p += __shfl_xor(p, 8);
  if (j == 0) invnorm[row] = 1.f / fmaxf(sqrtf(p), 1e-12f);
}

// Main: one block = (batch b, 64-d tile). NO operand LDS: each wave loads its
// A/B MFMA fragments straight from the bf16 table (per k-step, the 4 khi
// chunks of a row form one 64 B cacheline -> clean gathers, L2/L3-hot).
// Wave w = (qt = w>>1, dp = w&1) computes C tiles qt x {2dp, 2dp+1}.
__global__ __launch_bounds__(256) void knrm_main(
    const int* __restrict__ inputs_q, const int* __restrict__ inputs_d,
    const float* __restrict__ mask_d, const short* __restrict__ emb_bf16,
    const float* __restrict__ invnorm, float* __restrict__ partial)
{
  const int b    = blockIdx.y;
  const int dt   = blockIdx.x;
  const int tid  = threadIdx.x;
  const int wid  = tid >> 6;
  const int lane = tid & 63;
  const int khi  = lane >> 4;   // 0..3  (k-chunk 8*khi within each 32-k step)
  const int rl   = lane & 15;   // 0..15 (fragment row/col)
  const int qt   = wid >> 1;
  const int dp   = wid & 1;

  __shared__ float red[4][16][NBINS];   // 2.8 KB total LDS

  const int dbase = b * LD + dt * DTILE;
  const int tq  = inputs_q[b * LQ + 16 * qt + rl];
  const int td0 = inputs_d[dbase + 32 * dp + rl];
  const int td1 = inputs_d[dbase + 32 * dp + 16 + rl];
  const short8* arow = (const short8*)(emb_bf16 + (size_t)tq  * KPAD);
  const short8* b0r  = (const short8*)(emb_bf16 + (size_t)td0 * KPAD);
  const short8* b1r  = (const short8*)(emb_bf16 + (size_t)td1 * KPAD);

  floatx4 acc0 = {0.f, 0.f, 0.f, 0.f};
  floatx4 acc1 = {0.f, 0.f, 0.f, 0.f};
#pragma unroll
  for (int s = 0; s < NSTEP; ++s) {
    const short8 a  = arow[4 * s + khi];
    const short8 b0 = b0r [4 * s + khi];
    const short8 b1 = b1r [4 * s + khi];
    acc0 = __builtin_amdgcn_mfma_f32_16x16x32_bf16(a, b0, acc0, 0, 0, 0);
    acc1 = __builtin_amdgcn_mfma_f32_16x16x32_bf16(a, b1, acc1, 0, 0, 0);
  }

  // ---- epilogue: normalize, RBF bins, pool over this wave's 32 d-cols
  // C/D: col = rl, row = 4*khi + r. iq for row m via wave shuffle from lane m.
  const float iq_own = invnorm[tq];
  float iq[4];
#pragma unroll
  for (int r = 0; r < 4; ++r) iq[r] = __shfl(iq_own, 4 * khi + r);
  const float id0 = invnorm[td0], id1 = invnorm[td1];
  const float md0 = mask_d[dbase + 32 * dp + rl];
  const float md1 = mask_d[dbase + 32 * dp + 16 + rl];

  float ps[4][NBINS];
#pragma unroll
  for (int r = 0; r < 4; ++r) {
    const float s0 = acc0[r] * iq[r] * id0;
    const float s1 = acc1[r] * iq[r] * id1;
#pragma unroll
    for (int k = 0; k < NBINS; ++k) {
      const float d0 = s0 - c_mu[k];
      const float d1 = s1 - c_mu[k];
      ps[r][k] = md0 * __expf(-d0 * d0 * c_is2[k])
               + md1 * __expf(-d1 * d1 * c_is2[k]);
    }
  }

#pragma unroll
  for (int off = 1; off < 16; off <<= 1)
#pragma unroll
    for (int r = 0; r < 4; ++r)
#pragma unroll
      for (int k = 0; k < NBINS; ++k)
        ps[r][k] += __shfl_xor(ps[r][k], off);

  if (rl == 0)
#pragma unroll
    for (int r = 0; r < 4; ++r)
#pragma unroll
      for (int k = 0; k < NBINS; ++k)
        red[wid][4 * khi + r][k] = ps[r][k];
  __syncthreads();

  // partial layout: [b][q][k][dt] so finalize reads 16 contiguous floats
  for (int v = tid; v < LQ * NBINS; v += 256) {
    const int q = v / NBINS, k = v % NBINS;
    const float sv = (q < 16) ? (red[0][q][k] + red[1][q][k])
                              : (red[2][q - 16][k] + red[3][q - 16][k]);
    partial[((size_t)(b * LQ + q) * NBINS + k) * NDT + dt] = sv;
  }
}

// Finalize: reduce d-tiles, log, IDF attention weight, sum over q, dense+tanh.
__global__ __launch_bounds__(128) void knrm_finalize(
    const float* __restrict__ partial, const int* __restrict__ inputs_q,
    const float* __restrict__ mask_q, const float* __restrict__ attn_table,
    const float* __restrict__ idf_w, const float* __restrict__ idf_b,
    const float* __restrict__ dense_w, const float* __restrict__ dense_b,
    float* __restrict__ out)
{
  const int b   = blockIdx.x;
  const int tid = threadIdx.x;
  __shared__ float pool[LQ][NBINS];
  __shared__ float wq_s[LQ];
  __shared__ float lps[NBINS];

  for (int v = tid; v < LQ * NBINS; v += 128) {
    const int q = v / NBINS, k = v % NBINS;
    const float* p = partial + ((size_t)(b * LQ + q) * NBINS + k) * NDT;
    float s = 0.f;
#pragma unroll
    for (int t = 0; t < NDT; ++t) s += p[t];
    pool[q][k] = logf(fmaxf(s, 1e-10f));
  }
  if (tid < LQ) {
    const int tok = inputs_q[b * LQ + tid];
    wq_s[tid] = mask_q[b * LQ + tid] * (attn_table[tok] * idf_w[0] + idf_b[0]);
  }
  __syncthreads();
  if (tid < NBINS) {
    float s = 0.f;
    for (int q = 0; q < LQ; ++q) s += pool[q][tid] * wq_s[q];
    lps[tid] = 0.01f * s;
  }
  __syncthreads();
  if (tid == 0) {
    float z = dense_b[0];
    for (int k = 0; k < NBINS; ++k) z += lps[k] * dense_w[k];
    out[b] = tanhf(z);
  }
}

extern "C" void kernel_launch(void* const* d_in, const int* in_sizes, int n_in,
                              void* d_out, int out_size, void* d_ws, size_t ws_size,
                              hipStream_t stream) {
  const int*   inputs_q  = (const int*)d_in[0];
  const int*   inputs_d  = (const int*)d_in[1];
  const float* mask_q    = (const float*)d_in[2];
  const float* mask_d    = (const float*)d_in[3];
  const float* word_emb  = (const float*)d_in[4];
  const float* attn_tab  = (const float*)d_in[5];
  const float* idf_w     = (const float*)d_in[6];
  const float* idf_b     = (const float*)d_in[7];
  const float* dense_w   = (const float*)d_in[8];
  const float* dense_b   = (const float*)d_in[9];
  float* out = (float*)d_out;

  // ws layout (256 MiB available):
  //   partial  @ 0      : 64*32*11*16 f32  = 1.44 MB
  //   emb_bf16 @ 2 MB   : 50000*320 bf16   = 32 MB
  //   invnorm  @ 36 MB  : 50000 f32        = 0.2 MB
  char*  ws       = (char*)d_ws;
  float* partial  = (float*)ws;
  short* emb_bf16 = (short*)(ws + (2u  << 20));
  float* invnorm  = (float*)(ws + (36u << 20));

  knrm_vocab<<<VOCAB / 16, 256, 0, stream>>>(word_emb, emb_bf16, invnorm);
  dim3 grid(NDT, BATCH);
  knrm_main<<<grid, 256, 0, stream>>>(inputs_q, inputs_d, mask_d,
                                      emb_bf16, invnorm, partial);
  knrm_finalize<<<BATCH, 128, 0, stream>>>(partial, inputs_q, mask_q, attn_tab,
                                           idf_w, idf_b, dense_w, dense_b, out);
}